// Round 12
// baseline (575.682 us; speedup 1.0000x reference)
//
#include <hip/hip_runtime.h>
#include <hip/hip_bf16.h>
#include <hip/hip_cooperative_groups.h>

namespace cg = cooperative_groups;

#define N_NODES 50000
#define N_EDGES 800000
#define IN_DIM  256
#define OUT_DIM 128

#define NBINS        512      // bins of 98 rows: 512*98 = 50176 >= 50000 (verified)
#define ROWS_PER_BIN 98
#define HALF_ROWS    49
#define BIN_CAP      1920     // mean 1563 + 9 sigma
#define EPB          2048     // edges per bin-block
#define NB_BIN       391      // ceil(800000/2048)
#define NB_GEMM      391      // fallback k_fuse: 8 waves = 8 tiles/block
#define CUR_STRIDE   32       // one 128B cacheline per bin cursor
#define GRID         512      // coop grid: 2 blocks/CU (64KB LDS, lb(512,4))
#define GEMM_B0      121      // coop: gemm on blocks [121,512) -> 391 blocks

typedef __bf16 bf16x8 __attribute__((ext_vector_type(8)));
typedef float  f32x4  __attribute__((ext_vector_type(4)));

// bin = floor(row/98) via magic: (r*85599)>>23, exact for r < 50176 (verified R14).
__device__ __forceinline__ unsigned bin_of(unsigned r) { return (r * 85599u) >> 23; }
__device__ __forceinline__ float blo(unsigned u) { return __uint_as_float(u << 16); }
__device__ __forceinline__ float bhi(unsigned u) { return __uint_as_float(u & 0xffff0000u); }

// ---------------------------------------------------------------------------
// ws layout (bytes)
// ---------------------------------------------------------------------------
#define WF_OFF   0                      // 64 KB    : Wf bf16 frag-order [4096 slots][8]
#define SUP_OFF  65536                  // 12.8 MB  : support u32 [50000][64] planar-pair
#define BIN_OFF  12865536               // 7.86 MB  : binbuf int2[512*1920]
#define CUR_OFF  20729856               // 64 KB    : bin_cursor int[512*CUR_STRIDE]

// ===========================================================================
// FALLBACK PATH — verified R18 kernels, verbatim (151.2 us, passing).
// ===========================================================================
__global__ void k_prep(const float* __restrict__ W, __bf16* __restrict__ Wf,
                       int* __restrict__ bin_cursor) {
    int t = blockIdx.x * 256 + threadIdx.x;
    if (t < 32768) {
        int s = t >> 3, j = t & 7;
        int nrow = ((s >> 9) << 4) | (s & 15);                 // n*16 + m
        int k    = (((s >> 4) & 3) << 3) | (((s >> 6) & 7) << 5) | j;
        Wf[t] = (__bf16)W[k * OUT_DIM + nrow];
    }
    if (t < NBINS) bin_cursor[t * CUR_STRIDE] = t * BIN_CAP;
}

__global__ __launch_bounds__(512, 4) void k_fuse(const float* __restrict__ x,
                                                 const __bf16* __restrict__ Wf,
                                                 unsigned* __restrict__ sup32,
                                                 const int* __restrict__ rows,
                                                 const int* __restrict__ cols,
                                                 const float* __restrict__ vals,
                                                 int* __restrict__ bin_cursor,
                                                 int2* __restrict__ binbuf) {
    __shared__ union {
        uint4 sB[4096];                                   // 64 KB : gemm Wf tile
        struct { int cur[NBINS]; int base[NBINS]; } bin;  // 4 KB  : bin counters
    } sh;
    int t = threadIdx.x;

    if (blockIdx.x < NB_GEMM) {
        const uint4* wf4 = (const uint4*)Wf;
#pragma unroll
        for (int r = 0; r < 8; ++r) sh.sB[r * 512 + t] = wf4[r * 512 + t];
        __syncthreads();

        int  wave = t >> 6;
        int  lane = t & 63;
        long tile = (long)blockIdx.x * 8 + wave;
        if (tile >= 3125) return;
        int  m    = lane & 15;
        int  quad = lane >> 4;

        const float* aprow = x + (tile * 16 + m) * IN_DIM + quad * 8;

        float4 fa[16];
#pragma unroll
        for (int ks = 0; ks < 8; ++ks) {
            fa[2 * ks]     = *(const float4*)(aprow + ks * 32);
            fa[2 * ks + 1] = *(const float4*)(aprow + ks * 32 + 4);
        }
        bf16x8 ab[8];
#pragma unroll
        for (int ks = 0; ks < 8; ++ks) {
            float4 f0 = fa[2 * ks];
            float4 f1 = fa[2 * ks + 1];
            ab[ks] = (bf16x8){(__bf16)f0.x, (__bf16)f0.y, (__bf16)f0.z, (__bf16)f0.w,
                              (__bf16)f1.x, (__bf16)f1.y, (__bf16)f1.z, (__bf16)f1.w};
        }

        f32x4 acc[8];
#pragma unroll
        for (int n = 0; n < 8; ++n) acc[n] = (f32x4){0, 0, 0, 0};

        const __bf16* sbh = (const __bf16*)sh.sB;
#pragma unroll
        for (int ks = 0; ks < 8; ++ks) {
#pragma unroll
            for (int n = 0; n < 8; ++n) {
                bf16x8 bfr = *(const bf16x8*)(sbh + (((n * 8 + ks) * 64 + lane) << 3));
                acc[n] = __builtin_amdgcn_mfma_f32_16x16x32_bf16(ab[ks], bfr, acc[n], 0, 0, 0);
            }
        }

        unsigned* op = sup32 + (long)tile * 16 * 64;
#pragma unroll
        for (int r = 0; r < 4; ++r) {
#pragma unroll
            for (int n = 0; n < 4; ++n) {
                __bf16 lo = (__bf16)acc[n][r], hi = (__bf16)acc[n + 4][r];
                unsigned w = (unsigned)*(unsigned short*)&lo |
                             ((unsigned)*(unsigned short*)&hi << 16);
                op[(quad * 4 + r) * 64 + n * 16 + m] = w;
            }
        }
    } else {
        long e0 = (long)(blockIdx.x - NB_GEMM) * EPB;
        sh.bin.cur[t] = 0;
        __syncthreads();

        int2 rec[4];
        int  lrank[4];
        bool full = (e0 + EPB <= N_EDGES);

        if (full) {
#pragma unroll
            for (int k = 0; k < 4; ++k) {
                long e = e0 + k * 512 + t;
                unsigned r = (unsigned)rows[e];
                unsigned c = (unsigned)cols[e];
                float    w = vals[e];
                rec[k]   = make_int2((int)((r << 16) | c), __float_as_int(w));
                lrank[k] = atomicAdd(&sh.bin.cur[bin_of(r)], 1);
            }
        } else {
#pragma unroll
            for (int k = 0; k < 4; ++k) {
                long e = e0 + k * 512 + t;
                lrank[k] = -1;
                if (e < N_EDGES) {
                    unsigned r = (unsigned)rows[e];
                    unsigned c = (unsigned)cols[e];
                    float    w = vals[e];
                    rec[k]   = make_int2((int)((r << 16) | c), __float_as_int(w));
                    lrank[k] = atomicAdd(&sh.bin.cur[bin_of(r)], 1);
                }
            }
        }
        __syncthreads();

        sh.bin.base[t] = atomicAdd(&bin_cursor[t * CUR_STRIDE], sh.bin.cur[t]);
        __syncthreads();

#pragma unroll
        for (int k = 0; k < 4; ++k) {
            if (lrank[k] >= 0) {
                unsigned bn = bin_of(((unsigned)rec[k].x) >> 16);
                int dst = sh.bin.base[bn] + lrank[k];
                if (dst < (int)(bn + 1) * BIN_CAP)
                    binbuf[dst] = rec[k];
            }
        }
    }
}

__global__ __launch_bounds__(512, 4) void k_sg(const int* __restrict__ bin_cursor,
                                               const int2* __restrict__ binbuf,
                                               const unsigned* __restrict__ sup,
                                               const float* __restrict__ bias,
                                               float* __restrict__ out) {
    __shared__ int2 sorted_[BIN_CAP];
    __shared__ int  cnt[64], off[64], cur[64], s[64];
    int blk = blockIdx.x, t = threadIdx.x;
    int bin  = blk >> 1;
    int row0 = bin * ROWS_PER_BIN + (blk & 1) * HALF_ROWS;

    int n = bin_cursor[bin * CUR_STRIDE] - bin * BIN_CAP;
    n = n < 0 ? 0 : (n > BIN_CAP ? BIN_CAP : n);
    const int2* seg = binbuf + (long)bin * BIN_CAP;

    if (t < 64) cnt[t] = 0;
    __syncthreads();

    for (int i = t; i < n; i += 512) {
        int rl = (int)(((unsigned)seg[i].x) >> 16) - row0;
        if ((unsigned)rl < HALF_ROWS) atomicAdd(&cnt[rl], 1);
    }
    __syncthreads();

    int v = 0;
    if (t < 64) { v = cnt[t]; s[t] = v; }
    __syncthreads();
#pragma unroll
    for (int o = 1; o < 64; o <<= 1) {
        int xv = 0;
        if (t < 64 && t >= o) xv = s[t - o];
        __syncthreads();
        if (t < 64) s[t] += xv;
        __syncthreads();
    }
    if (t < 64) { off[t] = s[t] - v; cur[t] = 0; }
    __syncthreads();

    for (int i = t; i < n; i += 512) {
        int2 rec = seg[i];
        int rl = (int)(((unsigned)rec.x) >> 16) - row0;
        if ((unsigned)rl < HALF_ROWS)
            sorted_[off[rl] + atomicAdd(&cur[rl], 1)] = rec;
    }
    __syncthreads();

    int wave = t >> 6, lane = t & 63;
    float bb0 = bias[lane], bb1 = bias[64 + lane];

    for (int rl = wave; rl < HALF_ROWS; rl += 8) {
        int row = row0 + rl;
        if (row >= N_NODES) continue;
        int st = off[rl], nd = cnt[rl];
        float a0 = 0.f, a1 = 0.f;
        for (int i = 0; i < nd; i += 16) {
            int cidx[16]; unsigned u[16]; float vv[16];
#pragma unroll
            for (int j = 0; j < 16; ++j) {
                int ok = (i + j) < nd;
                int2 rec = sorted_[ok ? st + i + j : st];
                cidx[j] = rec.x & 0xffff;
                vv[j]   = ok ? __int_as_float(rec.y) : 0.f;
            }
#pragma unroll
            for (int j = 0; j < 16; ++j)
                u[j] = sup[(long)cidx[j] * 64 + lane];
#pragma unroll
            for (int j = 0; j < 16; ++j) {
                a0 += vv[j] * blo(u[j]);
                a1 += vv[j] * bhi(u[j]);
            }
        }
        out[(long)row * 128 + lane]      = a0 + bb0;
        out[(long)row * 128 + 64 + lane] = a1 + bb1;
    }
}

// ===========================================================================
// COOP PATH (R20): whole pipeline, ONE dispatch.  All cross-block handoffs
// (Wf, binbuf, sup32, bin_cursor) carry release/acquire __threadfence_system()
// around each grid.sync() — R19 lacked these; per Guideline 16, plain stores
// sit dirty in the writer's XCD L2 and readers on other XCDs get stale data.
// ===========================================================================
__global__ __launch_bounds__(512, 4) void k_all(
    const float* __restrict__ W, const float* __restrict__ x,
    const int* __restrict__ rows, const int* __restrict__ cols,
    const float* __restrict__ vals, const float* __restrict__ bias,
    float* __restrict__ out, __bf16* __restrict__ Wf,
    unsigned* __restrict__ sup32, int2* __restrict__ binbuf,
    int* __restrict__ bin_cursor) {
    __shared__ union {
        uint4 sB[4096];                                          // 64 KB : gemm Wf
        struct { int cur[NBINS]; int base[NBINS]; } bin;         // 4 KB
        struct { int2 sorted_[BIN_CAP];
                 int cnt[64], off[64], cur[64], s[64]; } sg;     // 16.4 KB
    } sh;
    int t   = threadIdx.x;
    int bid = blockIdx.x;

    // ================= P0: Wf prep + cursor init =================
    {
        int g = bid * 512 + t;
        if (g < 32768) {
            int s = g >> 3, j = g & 7;
            int nrow = ((s >> 9) << 4) | (s & 15);               // n*16 + m
            int k    = (((s >> 4) & 3) << 3) | (((s >> 6) & 7) << 5) | j;
            Wf[g] = (__bf16)W[k * OUT_DIM + nrow];
        }
        int c = g - 32768;
        if ((unsigned)c < NBINS) bin_cursor[c * CUR_STRIDE] = c * BIN_CAP;
    }
    __threadfence_system();              // release: Wf, cursors
    cg::this_grid().sync();
    __threadfence_system();              // acquire

    // ================= P1: bin (blocks 0..390), gemm (blocks 121..511) =====
    if (bid < NB_BIN) {
        long e0 = (long)bid * EPB;
        sh.bin.cur[t] = 0;
        __syncthreads();

        int2 rec[4];
        int  lrank[4];
        bool full = (e0 + EPB <= N_EDGES);

        if (full) {
#pragma unroll
            for (int k = 0; k < 4; ++k) {
                long e = e0 + k * 512 + t;
                unsigned r = (unsigned)rows[e];
                unsigned c = (unsigned)cols[e];
                float    w = vals[e];
                rec[k]   = make_int2((int)((r << 16) | c), __float_as_int(w));
                lrank[k] = atomicAdd(&sh.bin.cur[bin_of(r)], 1);
            }
        } else {
#pragma unroll
            for (int k = 0; k < 4; ++k) {
                long e = e0 + k * 512 + t;
                lrank[k] = -1;
                if (e < N_EDGES) {
                    unsigned r = (unsigned)rows[e];
                    unsigned c = (unsigned)cols[e];
                    float    w = vals[e];
                    rec[k]   = make_int2((int)((r << 16) | c), __float_as_int(w));
                    lrank[k] = atomicAdd(&sh.bin.cur[bin_of(r)], 1);
                }
            }
        }
        __syncthreads();

        sh.bin.base[t] = atomicAdd(&bin_cursor[t * CUR_STRIDE], sh.bin.cur[t]);
        __syncthreads();

#pragma unroll
        for (int k = 0; k < 4; ++k) {
            if (lrank[k] >= 0) {
                unsigned bn = bin_of(((unsigned)rec[k].x) >> 16);
                int dst = sh.bin.base[bn] + lrank[k];
                if (dst < (int)(bn + 1) * BIN_CAP)
                    binbuf[dst] = rec[k];
            }
        }
    }
    __syncthreads();    // union handoff: bin counters -> sB

    if (bid >= GEMM_B0) {
        const uint4* wf4 = (const uint4*)Wf;
#pragma unroll
        for (int r = 0; r < 8; ++r) sh.sB[r * 512 + t] = wf4[r * 512 + t];
        __syncthreads();

        int  wave = t >> 6;
        int  lane = t & 63;
        long tile = (long)(bid - GEMM_B0) * 8 + wave;  // 0..3127
        if (tile < 3125) {
            int m    = lane & 15;
            int quad = lane >> 4;

            const float* aprow = x + (tile * 16 + m) * IN_DIM + quad * 8;

            float4 fa[16];
#pragma unroll
            for (int ks = 0; ks < 8; ++ks) {
                fa[2 * ks]     = *(const float4*)(aprow + ks * 32);
                fa[2 * ks + 1] = *(const float4*)(aprow + ks * 32 + 4);
            }
            bf16x8 ab[8];
#pragma unroll
            for (int ks = 0; ks < 8; ++ks) {
                float4 f0 = fa[2 * ks];
                float4 f1 = fa[2 * ks + 1];
                ab[ks] = (bf16x8){(__bf16)f0.x, (__bf16)f0.y, (__bf16)f0.z, (__bf16)f0.w,
                                  (__bf16)f1.x, (__bf16)f1.y, (__bf16)f1.z, (__bf16)f1.w};
            }

            f32x4 acc[8];
#pragma unroll
            for (int n = 0; n < 8; ++n) acc[n] = (f32x4){0, 0, 0, 0};

            const __bf16* sbh = (const __bf16*)sh.sB;
#pragma unroll
            for (int ks = 0; ks < 8; ++ks) {
#pragma unroll
                for (int n = 0; n < 8; ++n) {
                    bf16x8 bfr = *(const bf16x8*)(sbh + (((n * 8 + ks) * 64 + lane) << 3));
                    acc[n] = __builtin_amdgcn_mfma_f32_16x16x32_bf16(ab[ks], bfr, acc[n], 0, 0, 0);
                }
            }

            unsigned* op = sup32 + (long)tile * 16 * 64;
#pragma unroll
            for (int r = 0; r < 4; ++r) {
#pragma unroll
                for (int n = 0; n < 4; ++n) {
                    __bf16 lo = (__bf16)acc[n][r], hi = (__bf16)acc[n + 4][r];
                    unsigned w = (unsigned)*(unsigned short*)&lo |
                                 ((unsigned)*(unsigned short*)&hi << 16);
                    op[(quad * 4 + r) * 64 + n * 16 + m] = w;
                }
            }
        }
    }
    __threadfence_system();              // release: binbuf, sup32, cursors
    cg::this_grid().sync();
    __threadfence_system();              // acquire

    // ================= P2: scatter-gather, both halves of bin `bid` ========
    {
        int wave = t >> 6, lane = t & 63;
        float bb0 = bias[lane], bb1 = bias[64 + lane];

        int bin = bid;
        int n = bin_cursor[bin * CUR_STRIDE] - bin * BIN_CAP;
        n = n < 0 ? 0 : (n > BIN_CAP ? BIN_CAP : n);
        const int2* seg = binbuf + (long)bin * BIN_CAP;

        for (int u = 0; u < 2; ++u) {
            int row0 = bin * ROWS_PER_BIN + u * HALF_ROWS;

            if (t < 64) sh.sg.cnt[t] = 0;
            __syncthreads();

            for (int i = t; i < n; i += 512) {
                int rl = (int)(((unsigned)seg[i].x) >> 16) - row0;
                if ((unsigned)rl < HALF_ROWS) atomicAdd(&sh.sg.cnt[rl], 1);
            }
            __syncthreads();

            int v = 0;
            if (t < 64) { v = sh.sg.cnt[t]; sh.sg.s[t] = v; }
            __syncthreads();
#pragma unroll
            for (int o = 1; o < 64; o <<= 1) {
                int xv = 0;
                if (t < 64 && t >= o) xv = sh.sg.s[t - o];
                __syncthreads();
                if (t < 64) sh.sg.s[t] += xv;
                __syncthreads();
            }
            if (t < 64) { sh.sg.off[t] = sh.sg.s[t] - v; sh.sg.cur[t] = 0; }
            __syncthreads();

            for (int i = t; i < n; i += 512) {
                int2 rec = seg[i];
                int rl = (int)(((unsigned)rec.x) >> 16) - row0;
                if ((unsigned)rl < HALF_ROWS)
                    sh.sg.sorted_[sh.sg.off[rl] + atomicAdd(&sh.sg.cur[rl], 1)] = rec;
            }
            __syncthreads();

            for (int rl = wave; rl < HALF_ROWS; rl += 8) {
                int row = row0 + rl;
                if (row >= N_NODES) continue;
                int st = sh.sg.off[rl], nd = sh.sg.cnt[rl];
                float a0 = 0.f, a1 = 0.f;
                for (int i = 0; i < nd; i += 16) {
                    int cidx[16]; unsigned uu[16]; float vv[16];
#pragma unroll
                    for (int j = 0; j < 16; ++j) {
                        int ok = (i + j) < nd;
                        int2 rec = sh.sg.sorted_[ok ? st + i + j : st];
                        cidx[j] = rec.x & 0xffff;
                        vv[j]   = ok ? __int_as_float(rec.y) : 0.f;
                    }
#pragma unroll
                    for (int j = 0; j < 16; ++j)
                        uu[j] = sup32[(long)cidx[j] * 64 + lane];
#pragma unroll
                    for (int j = 0; j < 16; ++j) {
                        a0 += vv[j] * blo(uu[j]);
                        a1 += vv[j] * bhi(uu[j]);
                    }
                }
                out[(long)row * 128 + lane]      = a0 + bb0;
                out[(long)row * 128 + 64 + lane] = a1 + bb1;
            }
            __syncthreads();
        }
    }
}

// ---------------------------------------------------------------------------
extern "C" void kernel_launch(void* const* d_in, const int* in_sizes, int n_in,
                              void* d_out, int out_size, void* d_ws, size_t ws_size,
                              hipStream_t stream) {
    const int*   adj_rows = (const int*)  d_in[0];
    const int*   adj_cols = (const int*)  d_in[1];
    const float* adj_vals = (const float*)d_in[2];
    const float* x        = (const float*)d_in[3];
    const float* W        = (const float*)d_in[4];
    const float* b        = (const float*)d_in[5];
    float* out = (float*)d_out;

    char* ws = (char*)d_ws;
    __bf16*   Wf         = (__bf16*)  (ws + WF_OFF);
    unsigned* sup32      = (unsigned*)(ws + SUP_OFF);
    int2*     binbuf     = (int2*)    (ws + BIN_OFF);
    int*      bin_cursor = (int*)     (ws + CUR_OFF);

    const float* W_a = W; const float* x_a = x;
    const int* rows_a = adj_rows; const int* cols_a = adj_cols;
    const float* vals_a = adj_vals; const float* b_a = b;
    void* args[] = {
        (void*)&W_a, (void*)&x_a, (void*)&rows_a, (void*)&cols_a,
        (void*)&vals_a, (void*)&b_a, (void*)&out, (void*)&Wf,
        (void*)&sup32, (void*)&binbuf, (void*)&bin_cursor
    };
    hipError_t err = hipLaunchCooperativeKernel((const void*)k_all, dim3(GRID),
                                                dim3(512), args, 0, stream);
    if (err != hipSuccess) {
        // Fallback: verified R18 three-kernel path (151.2 us, passing).
        k_prep<<<128, 256, 0, stream>>>(W, Wf, bin_cursor);
        k_fuse<<<NB_GEMM + NB_BIN, 512, 0, stream>>>(x, Wf, sup32,
                                                     adj_rows, adj_cols, adj_vals,
                                                     bin_cursor, binbuf);
        k_sg  <<<NBINS * 2, 512, 0, stream>>>(bin_cursor, binbuf, sup32, b, out);
    }
}

// Round 13
// 167.211 us; speedup vs baseline: 3.4428x; 3.4428x over previous
//
#include <hip/hip_runtime.h>
#include <hip/hip_bf16.h>

#define N_NODES 50000
#define N_EDGES 800000
#define IN_DIM  256
#define OUT_DIM 128

#define NBINS        512      // bins of 98 rows: 512*98 = 50176 >= 50000 (verified)
#define ROWS_PER_BIN 98
#define HALF_ROWS    49
#define BIN_CAP      1920     // mean 1563 + 9 sigma
#define EPB          2048     // edges per bin-block
#define NB_BIN       391      // ceil(800000/2048)
#define NB_GEMM      391      // k_fuse: 8 waves = 8 tiles/block (R18, verified)
#define CUR_STRIDE   32       // one 128B cacheline per bin cursor

typedef __bf16 bf16x8 __attribute__((ext_vector_type(8)));
typedef float  f32x4  __attribute__((ext_vector_type(4)));

// bin = floor(row/98) via magic: (r*85599)>>23, exact for r < 50176 (verified R14).
__device__ __forceinline__ unsigned bin_of(unsigned r) { return (r * 85599u) >> 23; }
__device__ __forceinline__ float blo(unsigned u) { return __uint_as_float(u << 16); }
__device__ __forceinline__ float bhi(unsigned u) { return __uint_as_float(u & 0xffff0000u); }

// ---------------------------------------------------------------------------
// ws layout (bytes)
// ---------------------------------------------------------------------------
#define WF_OFF   0                      // 64 KB    : Wf bf16 frag-order [4096 slots][8]
#define SUP_OFF  65536                  // 12.8 MB  : support u32 [50000][64] planar-pair
#define BIN_OFF  12865536               // 7.86 MB  : binbuf int2[512*1920]
#define CUR_OFF  20729856               // 64 KB    : bin_cursor int[512*CUR_STRIDE]

// ---------------------------------------------------------------------------
// prep (R12, verified): Wf = W in MFMA B-fragment order.
// ---------------------------------------------------------------------------
__global__ void k_prep(const float* __restrict__ W, __bf16* __restrict__ Wf,
                       int* __restrict__ bin_cursor) {
    int t = blockIdx.x * 256 + threadIdx.x;
    if (t < 32768) {
        int s = t >> 3, j = t & 7;
        int nrow = ((s >> 9) << 4) | (s & 15);                 // n*16 + m
        int k    = (((s >> 4) & 3) << 3) | (((s >> 6) & 7) << 5) | j;
        Wf[t] = (__bf16)W[k * OUT_DIM + nrow];
    }
    if (t < NBINS) bin_cursor[t * CUR_STRIDE] = t * BIN_CAP;
}

// ---------------------------------------------------------------------------
// k_fuse (R18, verified): 512-thread blocks; gemm blocks [0,391) with 8 waves
// sharing one 64 KB Wf staging; bin blocks [391,782) lean binning.
// ---------------------------------------------------------------------------
__global__ __launch_bounds__(512, 4) void k_fuse(const float* __restrict__ x,
                                                 const __bf16* __restrict__ Wf,
                                                 unsigned* __restrict__ sup32,
                                                 const int* __restrict__ rows,
                                                 const int* __restrict__ cols,
                                                 const float* __restrict__ vals,
                                                 int* __restrict__ bin_cursor,
                                                 int2* __restrict__ binbuf) {
    __shared__ union {
        uint4 sB[4096];                                   // 64 KB : gemm Wf tile
        struct { int cur[NBINS]; int base[NBINS]; } bin;  // 4 KB  : bin counters
    } sh;
    int t = threadIdx.x;

    if (blockIdx.x < NB_GEMM) {
        const uint4* wf4 = (const uint4*)Wf;
#pragma unroll
        for (int r = 0; r < 8; ++r) sh.sB[r * 512 + t] = wf4[r * 512 + t];
        __syncthreads();

        int  wave = t >> 6;
        int  lane = t & 63;
        long tile = (long)blockIdx.x * 8 + wave;
        if (tile >= 3125) return;
        int  m    = lane & 15;
        int  quad = lane >> 4;

        // A: lane (m,quad) reads row tile*16+m; 3125*16 == 50000 -> no guard.
        const float* aprow = x + (tile * 16 + m) * IN_DIM + quad * 8;

        float4 fa[16];
#pragma unroll
        for (int ks = 0; ks < 8; ++ks) {
            fa[2 * ks]     = *(const float4*)(aprow + ks * 32);
            fa[2 * ks + 1] = *(const float4*)(aprow + ks * 32 + 4);
        }
        bf16x8 ab[8];
#pragma unroll
        for (int ks = 0; ks < 8; ++ks) {
            float4 f0 = fa[2 * ks];
            float4 f1 = fa[2 * ks + 1];
            ab[ks] = (bf16x8){(__bf16)f0.x, (__bf16)f0.y, (__bf16)f0.z, (__bf16)f0.w,
                              (__bf16)f1.x, (__bf16)f1.y, (__bf16)f1.z, (__bf16)f1.w};
        }

        f32x4 acc[8];
#pragma unroll
        for (int n = 0; n < 8; ++n) acc[n] = (f32x4){0, 0, 0, 0};

        const __bf16* sbh = (const __bf16*)sh.sB;
#pragma unroll
        for (int ks = 0; ks < 8; ++ks) {
#pragma unroll
            for (int n = 0; n < 8; ++n) {
                // slot (n*8+ks)*64 + lane : consecutive lanes -> consecutive 16B
                bf16x8 bfr = *(const bf16x8*)(sbh + (((n * 8 + ks) * 64 + lane) << 3));
                acc[n] = __builtin_amdgcn_mfma_f32_16x16x32_bf16(ab[ks], bfr, acc[n], 0, 0, 0);
            }
        }

        // planar-pair epilogue (verified R7): word j = n*16+m = ch j | ch j+64
        unsigned* op = sup32 + (long)tile * 16 * 64;
#pragma unroll
        for (int r = 0; r < 4; ++r) {
#pragma unroll
            for (int n = 0; n < 4; ++n) {
                __bf16 lo = (__bf16)acc[n][r], hi = (__bf16)acc[n + 4][r];
                unsigned w = (unsigned)*(unsigned short*)&lo |
                             ((unsigned)*(unsigned short*)&hi << 16);
                op[(quad * 4 + r) * 64 + n * 16 + m] = w;
            }
        }
    } else {
        long e0 = (long)(blockIdx.x - NB_GEMM) * EPB;
        sh.bin.cur[t] = 0;
        __syncthreads();

        int2 rec[4];
        int  lrank[4];
        bool full = (e0 + EPB <= N_EDGES);

        if (full) {
#pragma unroll
            for (int k = 0; k < 4; ++k) {
                long e = e0 + k * 512 + t;
                unsigned r = (unsigned)rows[e];
                unsigned c = (unsigned)cols[e];
                float    w = vals[e];
                rec[k]   = make_int2((int)((r << 16) | c), __float_as_int(w));
                lrank[k] = atomicAdd(&sh.bin.cur[bin_of(r)], 1);
            }
        } else {
#pragma unroll
            for (int k = 0; k < 4; ++k) {
                long e = e0 + k * 512 + t;
                lrank[k] = -1;
                if (e < N_EDGES) {
                    unsigned r = (unsigned)rows[e];
                    unsigned c = (unsigned)cols[e];
                    float    w = vals[e];
                    rec[k]   = make_int2((int)((r << 16) | c), __float_as_int(w));
                    lrank[k] = atomicAdd(&sh.bin.cur[bin_of(r)], 1);
                }
            }
        }
        __syncthreads();

        sh.bin.base[t] = atomicAdd(&bin_cursor[t * CUR_STRIDE], sh.bin.cur[t]);
        __syncthreads();

#pragma unroll
        for (int k = 0; k < 4; ++k) {
            if (lrank[k] >= 0) {
                unsigned bn = bin_of(((unsigned)rec[k].x) >> 16);
                int dst = sh.bin.base[bn] + lrank[k];
                if (dst < (int)(bn + 1) * BIN_CAP)
                    binbuf[dst] = rec[k];
            }
        }
    }
}

// ---------------------------------------------------------------------------
// k_sg (R21): gather via global_load_lds DMA — queue-based MLP, zero VGPR
// per outstanding load (R13/R14/R15 showed the compiler collapses any
// register-resident gather window to ~4).  Each wave issues 16 per-lane 4B
// gathers into its private LDS strip, one s_waitcnt vmcnt(0), then consumes.
// Sort passes + planar-pair unpack = verified R17 bodies.
// ---------------------------------------------------------------------------
__global__ __launch_bounds__(512, 4) void k_sg(const int* __restrict__ bin_cursor,
                                               const int2* __restrict__ binbuf,
                                               const unsigned* __restrict__ sup,
                                               const float* __restrict__ bias,
                                               float* __restrict__ out) {
    __shared__ int2 sorted_[BIN_CAP];              // 15.4 KB
    __shared__ unsigned gbuf[8][16][64];           // 32 KB : per-wave DMA strips
    __shared__ int  cnt[64], off[64], cur[64], s[64];
    int blk = blockIdx.x, t = threadIdx.x;
    int bin  = blk >> 1;
    int row0 = bin * ROWS_PER_BIN + (blk & 1) * HALF_ROWS;

    int n = bin_cursor[bin * CUR_STRIDE] - bin * BIN_CAP;
    n = n < 0 ? 0 : (n > BIN_CAP ? BIN_CAP : n);
    const int2* seg = binbuf + (long)bin * BIN_CAP;

    if (t < 64) cnt[t] = 0;
    __syncthreads();

    // pass 1: count own-half rows
    for (int i = t; i < n; i += 512) {
        int rl = (int)(((unsigned)seg[i].x) >> 16) - row0;
        if ((unsigned)rl < HALF_ROWS) atomicAdd(&cnt[rl], 1);
    }
    __syncthreads();

    int v = 0;
    if (t < 64) { v = cnt[t]; s[t] = v; }
    __syncthreads();
#pragma unroll
    for (int o = 1; o < 64; o <<= 1) {
        int xv = 0;
        if (t < 64 && t >= o) xv = s[t - o];
        __syncthreads();
        if (t < 64) s[t] += xv;
        __syncthreads();
    }
    if (t < 64) { off[t] = s[t] - v; cur[t] = 0; }
    __syncthreads();

    // pass 2: scatter own-half records into row-sorted order
    for (int i = t; i < n; i += 512) {
        int2 rec = seg[i];
        int rl = (int)(((unsigned)rec.x) >> 16) - row0;
        if ((unsigned)rl < HALF_ROWS)
            sorted_[off[rl] + atomicAdd(&cur[rl], 1)] = rec;
    }
    __syncthreads();

    int wave = t >> 6, lane = t & 63;
    float bb0 = bias[lane], bb1 = bias[64 + lane];
    unsigned* gb = &gbuf[wave][0][0];

    for (int rl = wave; rl < HALF_ROWS; rl += 8) {
        int row = row0 + rl;
        if (row >= N_NODES) continue;
        int st = off[rl], nd = cnt[rl];
        float a0 = 0.f, a1 = 0.f;
        for (int i = 0; i < nd; i += 16) {
            float vv[16];
            // issue 16 per-lane DMA gathers (4B each) into this wave's strip
#pragma unroll
            for (int j = 0; j < 16; ++j) {
                int ok = (i + j) < nd;
                int2 rec = sorted_[ok ? st + i + j : st];
                vv[j] = ok ? __int_as_float(rec.y) : 0.f;
                const unsigned* gp = sup + (long)(rec.x & 0xffff) * 64 + lane;
                __builtin_amdgcn_global_load_lds(
                    (const __attribute__((address_space(1))) unsigned*)gp,
                    (__attribute__((address_space(3))) unsigned*)(gb + j * 64),
                    4, 0, 0);
            }
            asm volatile("s_waitcnt vmcnt(0)" ::: "memory");
#pragma unroll
            for (int j = 0; j < 16; ++j) {
                unsigned u = gb[j * 64 + lane];
                a0 += vv[j] * blo(u);
                a1 += vv[j] * bhi(u);
            }
        }
        out[(long)row * 128 + lane]      = a0 + bb0;
        out[(long)row * 128 + 64 + lane] = a1 + bb1;
    }
}

// ---------------------------------------------------------------------------
extern "C" void kernel_launch(void* const* d_in, const int* in_sizes, int n_in,
                              void* d_out, int out_size, void* d_ws, size_t ws_size,
                              hipStream_t stream) {
    const int*   adj_rows = (const int*)  d_in[0];
    const int*   adj_cols = (const int*)  d_in[1];
    const float* adj_vals = (const float*)d_in[2];
    const float* x        = (const float*)d_in[3];
    const float* W        = (const float*)d_in[4];
    const float* b        = (const float*)d_in[5];
    float* out = (float*)d_out;

    char* ws = (char*)d_ws;
    __bf16*   Wf         = (__bf16*)  (ws + WF_OFF);
    unsigned* sup32      = (unsigned*)(ws + SUP_OFF);
    int2*     binbuf     = (int2*)    (ws + BIN_OFF);
    int*      bin_cursor = (int*)     (ws + CUR_OFF);

    k_prep<<<128, 256, 0, stream>>>(W, Wf, bin_cursor);
    k_fuse<<<NB_GEMM + NB_BIN, 512, 0, stream>>>(x, Wf, sup32,
                                                 adj_rows, adj_cols, adj_vals,
                                                 bin_cursor, binbuf);
    k_sg  <<<NBINS * 2, 512, 0, stream>>>(bin_cursor, binbuf, sup32, b, out);
}

// Round 14
// 160.503 us; speedup vs baseline: 3.5867x; 1.0418x over previous
//
#include <hip/hip_runtime.h>
#include <hip/hip_bf16.h>

#define N_NODES 50000
#define N_EDGES 800000
#define IN_DIM  256
#define OUT_DIM 128

#define NBINS        512      // bins of 98 rows: 512*98 = 50176 >= 50000 (verified)
#define ROWS_PER_BIN 98
#define HALF_ROWS    49
#define BIN_CAP      1920     // mean 1563 + 9 sigma
#define EPB          2048     // edges per bin-block
#define NB_BIN       391      // ceil(800000/2048)
#define NB_GEMM      391      // k_fuse: 8 waves = 8 tiles/block (R18, verified)
#define CUR_STRIDE   32       // one 128B cacheline per bin cursor

typedef __bf16 bf16x8 __attribute__((ext_vector_type(8)));
typedef float  f32x4  __attribute__((ext_vector_type(4)));

// bin = floor(row/98) via magic: (r*85599)>>23, exact for r < 50176 (verified R14).
__device__ __forceinline__ unsigned bin_of(unsigned r) { return (r * 85599u) >> 23; }
__device__ __forceinline__ float blo(unsigned u) { return __uint_as_float(u << 16); }
__device__ __forceinline__ float bhi(unsigned u) { return __uint_as_float(u & 0xffff0000u); }

// ---------------------------------------------------------------------------
// ws layout (bytes)
// ---------------------------------------------------------------------------
#define WF_OFF   0                      // 64 KB    : Wf bf16 frag-order [4096 slots][8]
#define SUP_OFF  65536                  // 12.8 MB  : support u32 [50000][64] planar-pair
#define BIN_OFF  12865536               // 7.86 MB  : binbuf int2[512*1920]
#define CUR_OFF  20729856               // 64 KB    : bin_cursor int[512*CUR_STRIDE]

// ---------------------------------------------------------------------------
// prep (R12, verified): Wf = W in MFMA B-fragment order.
// ---------------------------------------------------------------------------
__global__ void k_prep(const float* __restrict__ W, __bf16* __restrict__ Wf,
                       int* __restrict__ bin_cursor) {
    int t = blockIdx.x * 256 + threadIdx.x;
    if (t < 32768) {
        int s = t >> 3, j = t & 7;
        int nrow = ((s >> 9) << 4) | (s & 15);                 // n*16 + m
        int k    = (((s >> 4) & 3) << 3) | (((s >> 6) & 7) << 5) | j;
        Wf[t] = (__bf16)W[k * OUT_DIM + nrow];
    }
    if (t < NBINS) bin_cursor[t * CUR_STRIDE] = t * BIN_CAP;
}

// ---------------------------------------------------------------------------
// k_fuse (R18, verified): 512-thread blocks; gemm blocks [0,391) with 8 waves
// sharing one 64 KB Wf staging; bin blocks [391,782) lean binning.
// ---------------------------------------------------------------------------
__global__ __launch_bounds__(512, 4) void k_fuse(const float* __restrict__ x,
                                                 const __bf16* __restrict__ Wf,
                                                 unsigned* __restrict__ sup32,
                                                 const int* __restrict__ rows,
                                                 const int* __restrict__ cols,
                                                 const float* __restrict__ vals,
                                                 int* __restrict__ bin_cursor,
                                                 int2* __restrict__ binbuf) {
    __shared__ union {
        uint4 sB[4096];                                   // 64 KB : gemm Wf tile
        struct { int cur[NBINS]; int base[NBINS]; } bin;  // 4 KB  : bin counters
    } sh;
    int t = threadIdx.x;

    if (blockIdx.x < NB_GEMM) {
        const uint4* wf4 = (const uint4*)Wf;
#pragma unroll
        for (int r = 0; r < 8; ++r) sh.sB[r * 512 + t] = wf4[r * 512 + t];
        __syncthreads();

        int  wave = t >> 6;
        int  lane = t & 63;
        long tile = (long)blockIdx.x * 8 + wave;
        if (tile >= 3125) return;
        int  m    = lane & 15;
        int  quad = lane >> 4;

        // A: lane (m,quad) reads row tile*16+m; 3125*16 == 50000 -> no guard.
        const float* aprow = x + (tile * 16 + m) * IN_DIM + quad * 8;

        float4 fa[16];
#pragma unroll
        for (int ks = 0; ks < 8; ++ks) {
            fa[2 * ks]     = *(const float4*)(aprow + ks * 32);
            fa[2 * ks + 1] = *(const float4*)(aprow + ks * 32 + 4);
        }
        bf16x8 ab[8];
#pragma unroll
        for (int ks = 0; ks < 8; ++ks) {
            float4 f0 = fa[2 * ks];
            float4 f1 = fa[2 * ks + 1];
            ab[ks] = (bf16x8){(__bf16)f0.x, (__bf16)f0.y, (__bf16)f0.z, (__bf16)f0.w,
                              (__bf16)f1.x, (__bf16)f1.y, (__bf16)f1.z, (__bf16)f1.w};
        }

        f32x4 acc[8];
#pragma unroll
        for (int n = 0; n < 8; ++n) acc[n] = (f32x4){0, 0, 0, 0};

        const __bf16* sbh = (const __bf16*)sh.sB;
#pragma unroll
        for (int ks = 0; ks < 8; ++ks) {
#pragma unroll
            for (int n = 0; n < 8; ++n) {
                // slot (n*8+ks)*64 + lane : consecutive lanes -> consecutive 16B
                bf16x8 bfr = *(const bf16x8*)(sbh + (((n * 8 + ks) * 64 + lane) << 3));
                acc[n] = __builtin_amdgcn_mfma_f32_16x16x32_bf16(ab[ks], bfr, acc[n], 0, 0, 0);
            }
        }

        // planar-pair epilogue (verified R7): word j = n*16+m = ch j | ch j+64
        unsigned* op = sup32 + (long)tile * 16 * 64;
#pragma unroll
        for (int r = 0; r < 4; ++r) {
#pragma unroll
            for (int n = 0; n < 4; ++n) {
                __bf16 lo = (__bf16)acc[n][r], hi = (__bf16)acc[n + 4][r];
                unsigned w = (unsigned)*(unsigned short*)&lo |
                             ((unsigned)*(unsigned short*)&hi << 16);
                op[(quad * 4 + r) * 64 + n * 16 + m] = w;
            }
        }
    } else {
        long e0 = (long)(blockIdx.x - NB_GEMM) * EPB;
        sh.bin.cur[t] = 0;
        __syncthreads();

        int2 rec[4];
        int  lrank[4];
        bool full = (e0 + EPB <= N_EDGES);

        if (full) {
#pragma unroll
            for (int k = 0; k < 4; ++k) {
                long e = e0 + k * 512 + t;
                unsigned r = (unsigned)rows[e];
                unsigned c = (unsigned)cols[e];
                float    w = vals[e];
                rec[k]   = make_int2((int)((r << 16) | c), __float_as_int(w));
                lrank[k] = atomicAdd(&sh.bin.cur[bin_of(r)], 1);
            }
        } else {
#pragma unroll
            for (int k = 0; k < 4; ++k) {
                long e = e0 + k * 512 + t;
                lrank[k] = -1;
                if (e < N_EDGES) {
                    unsigned r = (unsigned)rows[e];
                    unsigned c = (unsigned)cols[e];
                    float    w = vals[e];
                    rec[k]   = make_int2((int)((r << 16) | c), __float_as_int(w));
                    lrank[k] = atomicAdd(&sh.bin.cur[bin_of(r)], 1);
                }
            }
        }
        __syncthreads();

        sh.bin.base[t] = atomicAdd(&bin_cursor[t * CUR_STRIDE], sh.bin.cur[t]);
        __syncthreads();

#pragma unroll
        for (int k = 0; k < 4; ++k) {
            if (lrank[k] >= 0) {
                unsigned bn = bin_of(((unsigned)rec[k].x) >> 16);
                int dst = sh.bin.base[bn] + lrank[k];
                if (dst < (int)(bn + 1) * BIN_CAP)
                    binbuf[dst] = rec[k];
            }
        }
    }
}

// ---------------------------------------------------------------------------
// k_sg (R22): register gather reverted (R21's global_load_lds gather was
// SLOWER: per-lane scatter DMA serializes into the LDS write port).  New:
//  (a) DUAL-ROW gather — each wave runs two independent 8-wide gather
//      streams (rows rl, rl+8).  The compiler collapses one stream's window
//      to ~4; two disjoint chains double the effective MLP to ~8.
//  (b) XCD-aware half-pairing — both 49-row halves of a bin land on the
//      same XCD (round-robin blk&7), sharing the seg in one L2.
// Sort passes = verified R17 bodies.
// ---------------------------------------------------------------------------
__global__ __launch_bounds__(512, 4) void k_sg(const int* __restrict__ bin_cursor,
                                               const int2* __restrict__ binbuf,
                                               const unsigned* __restrict__ sup,
                                               const float* __restrict__ bias,
                                               float* __restrict__ out) {
    __shared__ int2 sorted_[BIN_CAP];              // 15.4 KB
    __shared__ int  cnt[64], off[64], cur[64], s[64];
    int blk = blockIdx.x, t = threadIdx.x;
    // XCD pairing: blk&7 = xcd (round-robin dispatch heuristic), 128 blocks
    // per xcd handle 64 bins x 2 halves.  Bijective for 1024 = 8*64*2.
    int bin  = (blk & 7) * 64 + (blk >> 4);
    int half = (blk >> 3) & 1;
    int row0 = bin * ROWS_PER_BIN + half * HALF_ROWS;

    int n = bin_cursor[bin * CUR_STRIDE] - bin * BIN_CAP;
    n = n < 0 ? 0 : (n > BIN_CAP ? BIN_CAP : n);
    const int2* seg = binbuf + (long)bin * BIN_CAP;

    if (t < 64) cnt[t] = 0;
    __syncthreads();

    // pass 1: count own-half rows
    for (int i = t; i < n; i += 512) {
        int rl = (int)(((unsigned)seg[i].x) >> 16) - row0;
        if ((unsigned)rl < HALF_ROWS) atomicAdd(&cnt[rl], 1);
    }
    __syncthreads();

    int v = 0;
    if (t < 64) { v = cnt[t]; s[t] = v; }
    __syncthreads();
#pragma unroll
    for (int o = 1; o < 64; o <<= 1) {
        int xv = 0;
        if (t < 64 && t >= o) xv = s[t - o];
        __syncthreads();
        if (t < 64) s[t] += xv;
        __syncthreads();
    }
    if (t < 64) { off[t] = s[t] - v; cur[t] = 0; }
    __syncthreads();

    // pass 2: scatter own-half records into row-sorted order
    for (int i = t; i < n; i += 512) {
        int2 rec = seg[i];
        int rl = (int)(((unsigned)rec.x) >> 16) - row0;
        if ((unsigned)rl < HALF_ROWS)
            sorted_[off[rl] + atomicAdd(&cur[rl], 1)] = rec;
    }
    __syncthreads();

    int wave = t >> 6, lane = t & 63;
    float bb0 = bias[lane], bb1 = bias[64 + lane];

    // dual-row gather: pairs (rlA, rlA+8); p=0..3 covers rows 0..48.
    for (int p = 0; p < 4; ++p) {
        int rlA = wave + p * 16;
        int rlB = rlA + 8;
        bool hasA = (rlA < HALF_ROWS) && (row0 + rlA < N_NODES);
        bool hasB = (rlB < HALF_ROWS) && (row0 + rlB < N_NODES);
        if (!hasA && !hasB) continue;
        int stA = 0, ndA = 0, stB = 0, ndB = 0;
        if (hasA) { stA = off[rlA]; ndA = cnt[rlA]; }
        if (hasB) { stB = off[rlB]; ndB = cnt[rlB]; }
        float a0A = 0.f, a1A = 0.f, a0B = 0.f, a1B = 0.f;

        int rounds = ndA > ndB ? ndA : ndB;
        for (int i = 0; i < rounds; i += 8) {
            unsigned uA[8], uB[8]; float vA[8], vB[8];
#pragma unroll
            for (int j = 0; j < 8; ++j) {
                int okA = (i + j) < ndA;
                int2 rA = sorted_[okA ? stA + i + j : stA];
                vA[j] = okA ? __int_as_float(rA.y) : 0.f;
                uA[j] = sup[(long)(((unsigned)rA.x) & 0xffffu) * 64 + lane];
                int okB = (i + j) < ndB;
                int2 rB = sorted_[okB ? stB + i + j : stB];
                vB[j] = okB ? __int_as_float(rB.y) : 0.f;
                uB[j] = sup[(long)(((unsigned)rB.x) & 0xffffu) * 64 + lane];
            }
#pragma unroll
            for (int j = 0; j < 8; ++j) {
                a0A += vA[j] * blo(uA[j]); a1A += vA[j] * bhi(uA[j]);
                a0B += vB[j] * blo(uB[j]); a1B += vB[j] * bhi(uB[j]);
            }
        }
        if (hasA) {
            int row = row0 + rlA;
            out[(long)row * 128 + lane]      = a0A + bb0;
            out[(long)row * 128 + 64 + lane] = a1A + bb1;
        }
        if (hasB) {
            int row = row0 + rlB;
            out[(long)row * 128 + lane]      = a0B + bb0;
            out[(long)row * 128 + 64 + lane] = a1B + bb1;
        }
    }
}

// ---------------------------------------------------------------------------
extern "C" void kernel_launch(void* const* d_in, const int* in_sizes, int n_in,
                              void* d_out, int out_size, void* d_ws, size_t ws_size,
                              hipStream_t stream) {
    const int*   adj_rows = (const int*)  d_in[0];
    const int*   adj_cols = (const int*)  d_in[1];
    const float* adj_vals = (const float*)d_in[2];
    const float* x        = (const float*)d_in[3];
    const float* W        = (const float*)d_in[4];
    const float* b        = (const float*)d_in[5];
    float* out = (float*)d_out;

    char* ws = (char*)d_ws;
    __bf16*   Wf         = (__bf16*)  (ws + WF_OFF);
    unsigned* sup32      = (unsigned*)(ws + SUP_OFF);
    int2*     binbuf     = (int2*)    (ws + BIN_OFF);
    int*      bin_cursor = (int*)     (ws + CUR_OFF);

    k_prep<<<128, 256, 0, stream>>>(W, Wf, bin_cursor);
    k_fuse<<<NB_GEMM + NB_BIN, 512, 0, stream>>>(x, Wf, sup32,
                                                 adj_rows, adj_cols, adj_vals,
                                                 bin_cursor, binbuf);
    k_sg  <<<NBINS * 2, 512, 0, stream>>>(bin_cursor, binbuf, sup32, b, out);
}

// Round 15
// 150.150 us; speedup vs baseline: 3.8340x; 1.0690x over previous
//
#include <hip/hip_runtime.h>
#include <hip/hip_bf16.h>

#define N_NODES 50000
#define N_EDGES 800000
#define IN_DIM  256
#define OUT_DIM 128

#define NBINS        512      // bins of 98 rows: 512*98 = 50176 >= 50000 (verified)
#define ROWS_PER_BIN 98
#define HALF_ROWS    49
#define BIN_CAP      1920     // mean 1563 + 9 sigma
#define EPB          2048     // edges per bin-block
#define NB_BIN       391      // ceil(800000/2048)
#define NB_GEMM      391      // k_fuse: 8 waves = 8 tiles/block (R18, verified)
#define CUR_STRIDE   32       // one 128B cacheline per bin cursor

typedef __bf16 bf16x8 __attribute__((ext_vector_type(8)));
typedef float  f32x4  __attribute__((ext_vector_type(4)));

// bin = floor(row/98) via magic: (r*85599)>>23, exact for r < 50176 (verified R14).
__device__ __forceinline__ unsigned bin_of(unsigned r) { return (r * 85599u) >> 23; }
__device__ __forceinline__ float blo(unsigned u) { return __uint_as_float(u << 16); }
__device__ __forceinline__ float bhi(unsigned u) { return __uint_as_float(u & 0xffff0000u); }

// ---------------------------------------------------------------------------
// ws layout (bytes)
// ---------------------------------------------------------------------------
#define WF_OFF   0                      // 64 KB    : Wf bf16 frag-order [4096 slots][8]
#define SUP_OFF  65536                  // 12.8 MB  : support u32 [50000][64] planar-pair
#define BIN_OFF  12865536               // 7.86 MB  : binbuf int2[512*1920]
#define CUR_OFF  20729856               // 64 KB    : bin_cursor int[512*CUR_STRIDE]

// ---------------------------------------------------------------------------
// prep (R12, verified): Wf = W in MFMA B-fragment order.
// ---------------------------------------------------------------------------
__global__ void k_prep(const float* __restrict__ W, __bf16* __restrict__ Wf,
                       int* __restrict__ bin_cursor) {
    int t = blockIdx.x * 256 + threadIdx.x;
    if (t < 32768) {
        int s = t >> 3, j = t & 7;
        int nrow = ((s >> 9) << 4) | (s & 15);                 // n*16 + m
        int k    = (((s >> 4) & 3) << 3) | (((s >> 6) & 7) << 5) | j;
        Wf[t] = (__bf16)W[k * OUT_DIM + nrow];
    }
    if (t < NBINS) bin_cursor[t * CUR_STRIDE] = t * BIN_CAP;
}

// ---------------------------------------------------------------------------
// k_fuse (R18, verified): 512-thread blocks; gemm blocks [0,391) with 8 waves
// sharing one 64 KB Wf staging; bin blocks [391,782) lean binning.
// ---------------------------------------------------------------------------
__global__ __launch_bounds__(512, 4) void k_fuse(const float* __restrict__ x,
                                                 const __bf16* __restrict__ Wf,
                                                 unsigned* __restrict__ sup32,
                                                 const int* __restrict__ rows,
                                                 const int* __restrict__ cols,
                                                 const float* __restrict__ vals,
                                                 int* __restrict__ bin_cursor,
                                                 int2* __restrict__ binbuf) {
    __shared__ union {
        uint4 sB[4096];                                   // 64 KB : gemm Wf tile
        struct { int cur[NBINS]; int base[NBINS]; } bin;  // 4 KB  : bin counters
    } sh;
    int t = threadIdx.x;

    if (blockIdx.x < NB_GEMM) {
        const uint4* wf4 = (const uint4*)Wf;
#pragma unroll
        for (int r = 0; r < 8; ++r) sh.sB[r * 512 + t] = wf4[r * 512 + t];
        __syncthreads();

        int  wave = t >> 6;
        int  lane = t & 63;
        long tile = (long)blockIdx.x * 8 + wave;
        if (tile >= 3125) return;
        int  m    = lane & 15;
        int  quad = lane >> 4;

        // A: lane (m,quad) reads row tile*16+m; 3125*16 == 50000 -> no guard.
        const float* aprow = x + (tile * 16 + m) * IN_DIM + quad * 8;

        float4 fa[16];
#pragma unroll
        for (int ks = 0; ks < 8; ++ks) {
            fa[2 * ks]     = *(const float4*)(aprow + ks * 32);
            fa[2 * ks + 1] = *(const float4*)(aprow + ks * 32 + 4);
        }
        bf16x8 ab[8];
#pragma unroll
        for (int ks = 0; ks < 8; ++ks) {
            float4 f0 = fa[2 * ks];
            float4 f1 = fa[2 * ks + 1];
            ab[ks] = (bf16x8){(__bf16)f0.x, (__bf16)f0.y, (__bf16)f0.z, (__bf16)f0.w,
                              (__bf16)f1.x, (__bf16)f1.y, (__bf16)f1.z, (__bf16)f1.w};
        }

        f32x4 acc[8];
#pragma unroll
        for (int n = 0; n < 8; ++n) acc[n] = (f32x4){0, 0, 0, 0};

        const __bf16* sbh = (const __bf16*)sh.sB;
#pragma unroll
        for (int ks = 0; ks < 8; ++ks) {
#pragma unroll
            for (int n = 0; n < 8; ++n) {
                // slot (n*8+ks)*64 + lane : consecutive lanes -> consecutive 16B
                bf16x8 bfr = *(const bf16x8*)(sbh + (((n * 8 + ks) * 64 + lane) << 3));
                acc[n] = __builtin_amdgcn_mfma_f32_16x16x32_bf16(ab[ks], bfr, acc[n], 0, 0, 0);
            }
        }

        // planar-pair epilogue (verified R7): word j = n*16+m = ch j | ch j+64
        unsigned* op = sup32 + (long)tile * 16 * 64;
#pragma unroll
        for (int r = 0; r < 4; ++r) {
#pragma unroll
            for (int n = 0; n < 4; ++n) {
                __bf16 lo = (__bf16)acc[n][r], hi = (__bf16)acc[n + 4][r];
                unsigned w = (unsigned)*(unsigned short*)&lo |
                             ((unsigned)*(unsigned short*)&hi << 16);
                op[(quad * 4 + r) * 64 + n * 16 + m] = w;
            }
        }
    } else {
        long e0 = (long)(blockIdx.x - NB_GEMM) * EPB;
        sh.bin.cur[t] = 0;
        __syncthreads();

        int2 rec[4];
        int  lrank[4];
        bool full = (e0 + EPB <= N_EDGES);

        if (full) {
#pragma unroll
            for (int k = 0; k < 4; ++k) {
                long e = e0 + k * 512 + t;
                unsigned r = (unsigned)rows[e];
                unsigned c = (unsigned)cols[e];
                float    w = vals[e];
                rec[k]   = make_int2((int)((r << 16) | c), __float_as_int(w));
                lrank[k] = atomicAdd(&sh.bin.cur[bin_of(r)], 1);
            }
        } else {
#pragma unroll
            for (int k = 0; k < 4; ++k) {
                long e = e0 + k * 512 + t;
                lrank[k] = -1;
                if (e < N_EDGES) {
                    unsigned r = (unsigned)rows[e];
                    unsigned c = (unsigned)cols[e];
                    float    w = vals[e];
                    rec[k]   = make_int2((int)((r << 16) | c), __float_as_int(w));
                    lrank[k] = atomicAdd(&sh.bin.cur[bin_of(r)], 1);
                }
            }
        }
        __syncthreads();

        sh.bin.base[t] = atomicAdd(&bin_cursor[t * CUR_STRIDE], sh.bin.cur[t]);
        __syncthreads();

#pragma unroll
        for (int k = 0; k < 4; ++k) {
            if (lrank[k] >= 0) {
                unsigned bn = bin_of(((unsigned)rec[k].x) >> 16);
                int dst = sh.bin.base[bn] + lrank[k];
                if (dst < (int)(bn + 1) * BIN_CAP)
                    binbuf[dst] = rec[k];
            }
        }
    }
}

// ---------------------------------------------------------------------------
// k_sg (R23): QUAD-EDGE WIDE GATHER.  Evidence R13/R14/R21/R22: the compiler
// holds ~4 load instructions in flight no matter how many independent chains.
// So raise BYTES per instruction instead: each 16-lane group loads one FULL
// sup row (uint4 = 16B/lane x 16 lanes = 256 B) -> one instruction per edge,
// 4-instruction window covers 16 edges = 4 KB in flight (4x R17).
// Lane owns channel quad {4k..4k+3, 64+4k..67+4k} (planar-pair, verified R7);
// row-end 2-step shfl_xor butterfly over the 4 edge-groups; lanes 0-15 write
// two coalesced float4s.  Sort passes = verified R17 bodies; bin = blk>>1.
// ---------------------------------------------------------------------------
__global__ __launch_bounds__(512, 4) void k_sg(const int* __restrict__ bin_cursor,
                                               const int2* __restrict__ binbuf,
                                               const unsigned* __restrict__ sup,
                                               const float* __restrict__ bias,
                                               float* __restrict__ out) {
    __shared__ int2 sorted_[BIN_CAP];              // 15.4 KB
    __shared__ int  cnt[64], off[64], cur[64], s[64];
    int blk = blockIdx.x, t = threadIdx.x;
    int bin  = blk >> 1;
    int row0 = bin * ROWS_PER_BIN + (blk & 1) * HALF_ROWS;

    int n = bin_cursor[bin * CUR_STRIDE] - bin * BIN_CAP;
    n = n < 0 ? 0 : (n > BIN_CAP ? BIN_CAP : n);
    const int2* seg = binbuf + (long)bin * BIN_CAP;

    if (t < 64) cnt[t] = 0;
    __syncthreads();

    // pass 1: count own-half rows
    for (int i = t; i < n; i += 512) {
        int rl = (int)(((unsigned)seg[i].x) >> 16) - row0;
        if ((unsigned)rl < HALF_ROWS) atomicAdd(&cnt[rl], 1);
    }
    __syncthreads();

    int v = 0;
    if (t < 64) { v = cnt[t]; s[t] = v; }
    __syncthreads();
#pragma unroll
    for (int o = 1; o < 64; o <<= 1) {
        int xv = 0;
        if (t < 64 && t >= o) xv = s[t - o];
        __syncthreads();
        if (t < 64) s[t] += xv;
        __syncthreads();
    }
    if (t < 64) { off[t] = s[t] - v; cur[t] = 0; }
    __syncthreads();

    // pass 2: scatter own-half records into row-sorted order
    for (int i = t; i < n; i += 512) {
        int2 rec = seg[i];
        int rl = (int)(((unsigned)rec.x) >> 16) - row0;
        if ((unsigned)rl < HALF_ROWS)
            sorted_[off[rl] + atomicAdd(&cur[rl], 1)] = rec;
    }
    __syncthreads();

    int wave = t >> 6, lane = t & 63;
    int g = lane >> 4;          // edge-group 0..3
    int k = lane & 15;          // word-quad index within the sup row
    float4 bbLo = ((const float4*)bias)[k];
    float4 bbHi = ((const float4*)bias)[k + 16];

    for (int rl = wave; rl < HALF_ROWS; rl += 8) {
        int row = row0 + rl;
        if (row >= N_NODES) continue;
        int st = off[rl], nd = cnt[rl];
        float aL0 = 0.f, aL1 = 0.f, aL2 = 0.f, aL3 = 0.f;
        float aH0 = 0.f, aH1 = 0.f, aH2 = 0.f, aH3 = 0.f;

        for (int i = 0; i < nd; i += 16) {
            uint4 u[4]; float vv[4];
            // 4 load instructions cover 16 edges: instr j, group g -> edge i+4j+g
#pragma unroll
            for (int j = 0; j < 4; ++j) {
                int e  = i + 4 * j + g;
                int ok = e < nd;
                int2 rec = sorted_[ok ? st + e : st];
                vv[j] = ok ? __int_as_float(rec.y) : 0.f;
                u[j]  = *(const uint4*)(sup + (long)(((unsigned)rec.x) & 0xffffu) * 64 + k * 4);
            }
#pragma unroll
            for (int j = 0; j < 4; ++j) {
                aL0 += vv[j] * blo(u[j].x); aH0 += vv[j] * bhi(u[j].x);
                aL1 += vv[j] * blo(u[j].y); aH1 += vv[j] * bhi(u[j].y);
                aL2 += vv[j] * blo(u[j].z); aH2 += vv[j] * bhi(u[j].z);
                aL3 += vv[j] * blo(u[j].w); aH3 += vv[j] * bhi(u[j].w);
            }
        }

        // reduce the 4 edge-groups (lane bits 4,5): butterfly over 16, 32
#pragma unroll
        for (int mask = 16; mask < 64; mask <<= 1) {
            aL0 += __shfl_xor(aL0, mask, 64);
            aL1 += __shfl_xor(aL1, mask, 64);
            aL2 += __shfl_xor(aL2, mask, 64);
            aL3 += __shfl_xor(aL3, mask, 64);
            aH0 += __shfl_xor(aH0, mask, 64);
            aH1 += __shfl_xor(aH1, mask, 64);
            aH2 += __shfl_xor(aH2, mask, 64);
            aH3 += __shfl_xor(aH3, mask, 64);
        }
        if (g == 0) {
            float4 oLo = {aL0 + bbLo.x, aL1 + bbLo.y, aL2 + bbLo.z, aL3 + bbLo.w};
            float4 oHi = {aH0 + bbHi.x, aH1 + bbHi.y, aH2 + bbHi.z, aH3 + bbHi.w};
            *(float4*)(out + (long)row * 128 + 4 * k)      = oLo;
            *(float4*)(out + (long)row * 128 + 64 + 4 * k) = oHi;
        }
    }
}

// ---------------------------------------------------------------------------
extern "C" void kernel_launch(void* const* d_in, const int* in_sizes, int n_in,
                              void* d_out, int out_size, void* d_ws, size_t ws_size,
                              hipStream_t stream) {
    const int*   adj_rows = (const int*)  d_in[0];
    const int*   adj_cols = (const int*)  d_in[1];
    const float* adj_vals = (const float*)d_in[2];
    const float* x        = (const float*)d_in[3];
    const float* W        = (const float*)d_in[4];
    const float* b        = (const float*)d_in[5];
    float* out = (float*)d_out;

    char* ws = (char*)d_ws;
    __bf16*   Wf         = (__bf16*)  (ws + WF_OFF);
    unsigned* sup32      = (unsigned*)(ws + SUP_OFF);
    int2*     binbuf     = (int2*)    (ws + BIN_OFF);
    int*      bin_cursor = (int*)     (ws + CUR_OFF);

    k_prep<<<128, 256, 0, stream>>>(W, Wf, bin_cursor);
    k_fuse<<<NB_GEMM + NB_BIN, 512, 0, stream>>>(x, Wf, sup32,
                                                 adj_rows, adj_cols, adj_vals,
                                                 bin_cursor, binbuf);
    k_sg  <<<NBINS * 2, 512, 0, stream>>>(bin_cursor, binbuf, sup32, b, out);
}